// Round 6
// baseline (272.378 us; speedup 1.0000x reference)
//
#include <hip/hip_runtime.h>
#include <hip/hip_bf16.h>
#include <math.h>

#define B_SZ 8
#define L_SZ 4096
#define D_SZ 1024
#define CHT  64
#define NCH  (L_SZ / CHT)

typedef __bf16 bf16_t;
typedef bf16_t bf16x8 __attribute__((ext_vector_type(8)));
typedef bf16_t bf16x4 __attribute__((ext_vector_type(4)));
typedef float  f32x4  __attribute__((ext_vector_type(4)));

#define BM 256
#define BN 128
#define BK 64
#define NT (1024 / BK)     // 16 K-tiles
#define BUFB 49152         // bytes per staging buffer: A 32KB + B 16KB
#define EP_P 68            // epilogue strip padded width (f32)

__device__ __forceinline__ void gld16(const void* g, void* l) {
  __builtin_amdgcn_global_load_lds(
      (const __attribute__((address_space(1))) void*)g,
      (__attribute__((address_space(3))) void*)l, 16, 0, 0);
}

// C[m,n] = sum_k A[m,k]*Wt[n,k]; A,Wt bf16 row-major [.,1024]; C bf16.
// 256x128 tile, 8 waves (4Mx2N, wave tile 64x64), BK=64, 3-buffer counted-vmcnt
// ring + 2-phase-per-K-tile interleave (m201-style: per phase ~12 ds_read_b128,
// split staging, barrier, setprio-wrapped 16-MFMA cluster, barrier).
// 3-bit XOR chunk swizzle: LDS[row][ch] = global[row][ch ^ (row&7)] (16B chunks).
// MODE 0: fused per-64-chunk scan in epilogue, chunk finals -> cf.
// MODE 1: plain bf16 store.
template<int MODE>
__global__ __launch_bounds__(512, 2)
void gemm256(const bf16_t* __restrict__ A, const bf16_t* __restrict__ Wt,
             bf16_t* __restrict__ Cg, const float* __restrict__ pw,
             float* __restrict__ cf) {
  __shared__ __align__(16) char smem[3 * BUFB];   // 144KB; epilogue strip aliases
  const int tid  = threadIdx.x;
  const int lane = tid & 63;
  const int wave = tid >> 6;
  const int wm = wave >> 1, wn = wave & 1;
  const int fr = lane & 15, g = lane >> 4;

  // XCD-chunked bijective swizzle: 1024 blocks = 8 XCDs x 128; per XCD bx fastest
  const int flat = (blockIdx.x & 7) * 128 + (blockIdx.x >> 3);
  const int bx = flat & 7, by = flat >> 3;
  const int brow = by * BM, bcol = bx * BN;

  // ---- staging (write side): LDS linear dest, global source chunk-swizzled
  const int sr = lane >> 3;             // sub-row 0..7
  const int sc = (lane & 7) ^ sr;       // swizzled 16B chunk
  const bf16_t* a0 = A  + (size_t)(brow + wave * 8 + sr) * 1024 + sc * 8;
  const bf16_t* b0 = Wt + (size_t)(bcol + wave * 8 + sr) * 1024 + sc * 8;

  // ---- read side: global chunk c of row r lives at LDS chunk c^(r&7); r&7 == fr&7
  const int c0 = ((g)     ^ (fr & 7)) << 4;     // kstep 0 chunk byte offset
  const int c1 = ((4 + g) ^ (fr & 7)) << 4;     // kstep 1
  const int arowB = (wm * 64 + fr) * 128;       // + mi*2048
  const int browB = (wn * 64 + fr) * 128;       // + ni*2048 (within B region)

  f32x4 acc[4][4] = {};

#define STAGE_A(BU, T) { \
    char* d_ = smem + (BU) * BUFB + wave * 1024; \
    const size_t ko_ = (size_t)(T) * BK; \
    gld16(a0 + ko_, d_); \
    gld16(a0 + (size_t)64 * 1024 + ko_, d_ + 8192); \
    gld16(a0 + (size_t)128 * 1024 + ko_, d_ + 16384); \
    gld16(a0 + (size_t)192 * 1024 + ko_, d_ + 24576); \
  }
#define STAGE_B(BU, T) { \
    char* d_ = smem + (BU) * BUFB + wave * 1024; \
    const size_t ko_ = (size_t)(T) * BK; \
    gld16(b0 + ko_, d_ + 32768); \
    gld16(b0 + (size_t)64 * 1024 + ko_, d_ + 40960); \
  }

  STAGE_A(0, 0) STAGE_B(0, 0)
  STAGE_A(1, 1) STAGE_B(1, 1)
  asm volatile("s_waitcnt vmcnt(6)" ::: "memory");   // tile 0 resident
  __builtin_amdgcn_s_barrier();
  asm volatile("" ::: "memory");

  int bu = 0, bs = 2;
  for (int t = 0; t < NT; ++t) {
    const char* aB = smem + bu * BUFB;
    const char* bB = aB + 32768;
    bf16x8 af[4][2], bfv[4][2];
    // ===== phase 1: A-frags mi 0..1 + all B-frags (12 ds_read); stage A of t+2
#pragma unroll
    for (int mi = 0; mi < 2; ++mi) {
      af[mi][0] = *(const bf16x8*)(aB + arowB + mi * 2048 + c0);
      af[mi][1] = *(const bf16x8*)(aB + arowB + mi * 2048 + c1);
    }
#pragma unroll
    for (int ni = 0; ni < 4; ++ni) {
      bfv[ni][0] = *(const bf16x8*)(bB + browB + ni * 2048 + c0);
      bfv[ni][1] = *(const bf16x8*)(bB + browB + ni * 2048 + c1);
    }
    if (t + 2 < NT) STAGE_A(bs, t + 2)
    __builtin_amdgcn_s_barrier();
    asm volatile("" ::: "memory");
    __builtin_amdgcn_s_setprio(1);
#pragma unroll
    for (int mi = 0; mi < 2; ++mi)
#pragma unroll
      for (int ni = 0; ni < 4; ++ni) {
        acc[mi][ni] = __builtin_amdgcn_mfma_f32_16x16x32_bf16(af[mi][0], bfv[ni][0], acc[mi][ni], 0, 0, 0);
        acc[mi][ni] = __builtin_amdgcn_mfma_f32_16x16x32_bf16(af[mi][1], bfv[ni][1], acc[mi][ni], 0, 0, 0);
      }
    __builtin_amdgcn_s_setprio(0);
    __builtin_amdgcn_s_barrier();
    asm volatile("" ::: "memory");
    // ===== phase 2: A-frags mi 2..3 (4 ds_read; B reused in regs); stage B of t+2
#pragma unroll
    for (int mi = 2; mi < 4; ++mi) {
      af[mi][0] = *(const bf16x8*)(aB + arowB + mi * 2048 + c0);
      af[mi][1] = *(const bf16x8*)(aB + arowB + mi * 2048 + c1);
    }
    if (t + 2 < NT) STAGE_B(bs, t + 2)
    __builtin_amdgcn_s_barrier();
    asm volatile("" ::: "memory");
    __builtin_amdgcn_s_setprio(1);
#pragma unroll
    for (int mi = 2; mi < 4; ++mi)
#pragma unroll
      for (int ni = 0; ni < 4; ++ni) {
        acc[mi][ni] = __builtin_amdgcn_mfma_f32_16x16x32_bf16(af[mi][0], bfv[ni][0], acc[mi][ni], 0, 0, 0);
        acc[mi][ni] = __builtin_amdgcn_mfma_f32_16x16x32_bf16(af[mi][1], bfv[ni][1], acc[mi][ni], 0, 0, 0);
      }
    __builtin_amdgcn_s_setprio(0);
    if (t + 2 < NT) asm volatile("s_waitcnt vmcnt(6)" ::: "memory");
    else            asm volatile("s_waitcnt vmcnt(0)" ::: "memory");
    __builtin_amdgcn_s_barrier();
    asm volatile("" ::: "memory");
    bu = (bu == 2) ? 0 : bu + 1;
    bs = (bs == 2) ? 0 : bs + 1;
  }
#undef STAGE_A
#undef STAGE_B

  // ---- epilogue: 2 column-strips of 64; strip LDS [256][EP_P] f32 aliases staging
  __syncthreads();
  float* strip = (float*)smem;
  const int bb  = by >> 4;             // batch (16 row-blocks per batch)
  const int cg0 = (by & 15) * 4;       // first global chunk of this block
#pragma unroll 1
  for (int q = 0; q < 2; ++q) {
    if (wn == q) {
#pragma unroll
      for (int mi = 0; mi < 4; ++mi)
#pragma unroll
        for (int ni = 0; ni < 4; ++ni)
#pragma unroll
          for (int r = 0; r < 4; ++r)
            strip[(wm * 64 + mi * 16 + g * 4 + r) * EP_P + ni * 16 + fr] = acc[mi][ni][r];
    }
    __syncthreads();
    if constexpr (MODE == 0) {
      if (tid < 256) {
        const int col = tid & 63;
        const int ch  = tid >> 6;       // chunk 0..3; one wave per chunk
        const int d   = bcol + q * 64 + col;
        const float a = pw[d];          // pw[0][d] = a_d
        float s = 0.f;
#pragma unroll 1
        for (int grp = 0; grp < 4; ++grp) {
          float v[16];
#pragma unroll
          for (int u = 0; u < 16; ++u) v[u] = strip[(ch * 64 + grp * 16 + u) * EP_P + col];
#pragma unroll
          for (int u = 0; u < 16; ++u) { s = a * s + v[u]; v[u] = s; }
#pragma unroll
          for (int u = 0; u < 16; ++u) strip[(ch * 64 + grp * 16 + u) * EP_P + col] = v[u];
        }
        cf[((size_t)(bb * NCH + cg0 + ch)) * D_SZ + d] = s;
      }
      __syncthreads();
    }
#pragma unroll
    for (int j = 0; j < 4; ++j) {
      const int u = j * 512 + tid;
      const int row = u >> 3;
      const int cu = (u & 7) * 8;
      f32x4 lo = *(const f32x4*)&strip[row * EP_P + cu];
      f32x4 hi = *(const f32x4*)&strip[row * EP_P + cu + 4];
      bf16x8 h;
#pragma unroll
      for (int jj = 0; jj < 4; ++jj) { h[jj] = (bf16_t)lo[jj]; h[4 + jj] = (bf16_t)hi[jj]; }
      *(bf16x8*)&Cg[(size_t)(brow + row) * 1024 + bcol + q * 64 + cu] = h;
    }
    __syncthreads();
  }
}

// fp32 -> bf16 grid-stride convert
__global__ __launch_bounds__(256)
void conv_bf16_k(const float* __restrict__ src, bf16_t* __restrict__ dst, int n) {
  int i = (blockIdx.x * 256 + threadIdx.x) * 4;
  const int stride = gridDim.x * 256 * 4;
  for (; i < n; i += stride) {
    f32x4 v = *(const f32x4*)(src + i);
    bf16x4 h;
#pragma unroll
    for (int j = 0; j < 4; ++j) h[j] = (bf16_t)v[j];
    *(bf16x4*)(dst + i) = h;
  }
}

// pw[t][d] = a_d^(t+1)
__global__ __launch_bounds__(256)
void pow_k(const float* __restrict__ log_a, float* __restrict__ pw) {
  const int t = blockIdx.x;
  const int d = threadIdx.x * 4;
#pragma unroll
  for (int j = 0; j < 4; ++j)
    pw[t * D_SZ + d + j] = expf(log_a[d + j] * (float)(t + 1));
}

// sequential scan over chunk finals with factor a^CHT, in place
__global__ __launch_bounds__(256)
void scan_carry_k(const float* __restrict__ log_a, float* __restrict__ cf) {
  const int d = blockIdx.x * 256 + threadIdx.x;
  const int b = blockIdx.y;
  const float aT = expf(log_a[d] * (float)CHT);
  float s = 0.f;
  for (int c = 0; c < NCH; ++c) {
    const size_t idx = ((size_t)(b * NCH + c)) * D_SZ + d;
    s = aT * s + cf[idx];
    cf[idx] = s;
  }
}

// states = xb16 + a^(t+1)*S_{c-1}; write bf16 for GEMM2
__global__ __launch_bounds__(128)
void scan_apply_k(const bf16_t* __restrict__ xb16, const float* __restrict__ pw,
                  const float* __restrict__ cf, bf16_t* __restrict__ xs16) {
  const int d8 = threadIdx.x * 8;
  const int l = blockIdx.x;
  const int b = blockIdx.y;
  const int c = l >> 6;
  const int t = l & (CHT - 1);
  const size_t idx = ((size_t)(b * L_SZ + l)) * D_SZ + d8;
  bf16x8 hv = *(const bf16x8*)(xb16 + idx);
  float s[8];
#pragma unroll
  for (int j = 0; j < 8; ++j) s[j] = (float)hv[j];
  if (c > 0) {
    f32x4 p0  = *(const f32x4*)(pw + t * D_SZ + d8);
    f32x4 p1  = *(const f32x4*)(pw + t * D_SZ + d8 + 4);
    const float* cb = cf + ((size_t)(b * NCH + (c - 1))) * D_SZ + d8;
    f32x4 v0 = *(const f32x4*)cb;
    f32x4 v1 = *(const f32x4*)(cb + 4);
#pragma unroll
    for (int j = 0; j < 4; ++j) { s[j] += p0[j] * v0[j]; s[4 + j] += p1[j] * v1[j]; }
  }
  bf16x8 h;
#pragma unroll
  for (int j = 0; j < 8; ++j) h[j] = (bf16_t)s[j];
  *(bf16x8*)(xs16 + idx) = h;
}

// LayerNorm over D=1024 (bf16 input, fp32 output), one block per row
__global__ __launch_bounds__(256)
void ln_k(const bf16_t* __restrict__ y, const float* __restrict__ gamma,
          const float* __restrict__ beta, float* __restrict__ out) {
  const size_t row = blockIdx.x;
  const int tid = threadIdx.x;
  bf16x4 h = *(const bf16x4*)(y + row * D_SZ + tid * 4);
  float v[4];
#pragma unroll
  for (int j = 0; j < 4; ++j) v[j] = (float)h[j];
  float s  = v[0] + v[1] + v[2] + v[3];
  float sq = v[0] * v[0] + v[1] * v[1] + v[2] * v[2] + v[3] * v[3];
#pragma unroll
  for (int off = 32; off; off >>= 1) {
    s  += __shfl_down(s, off);
    sq += __shfl_down(sq, off);
  }
  __shared__ float red[8];
  const int wid = tid >> 6;
  if ((tid & 63) == 0) { red[wid] = s; red[4 + wid] = sq; }
  __syncthreads();
  s  = red[0] + red[1] + red[2] + red[3];
  sq = red[4] + red[5] + red[6] + red[7];
  const float mean = s * (1.f / D_SZ);
  const float var  = sq * (1.f / D_SZ) - mean * mean;
  const float inv  = rsqrtf(var + 1e-5f);
  f32x4 gm = *(const f32x4*)(gamma + tid * 4);
  f32x4 bt = *(const f32x4*)(beta  + tid * 4);
  f32x4 o;
#pragma unroll
  for (int j = 0; j < 4; ++j) o[j] = (v[j] - mean) * inv * gm[j] + bt[j];
  *(f32x4*)(out + row * D_SZ + tid * 4) = o;
}

extern "C" void kernel_launch(void* const* d_in, const int* in_sizes, int n_in,
                              void* d_out, int out_size, void* d_ws, size_t ws_size,
                              hipStream_t stream) {
  const float* u     = (const float*)d_in[0];
  const float* log_a = (const float*)d_in[1];
  const float* W_b   = (const float*)d_in[2];
  const float* W_c   = (const float*)d_in[3];
  const float* gamma = (const float*)d_in[4];
  const float* beta  = (const float*)d_in[5];
  float* out = (float*)d_out;

  const size_t NBLD = (size_t)B_SZ * L_SZ * D_SZ;
  bf16_t* u16  = (bf16_t*)d_ws;             // bf16 u; xs16 aliases after GEMM1
  bf16_t* xb16 = u16 + NBLD;                // GEMM1 out (locally scanned); y16 aliases
  bf16_t* wb16 = xb16 + NBLD;
  bf16_t* wc16 = wb16 + (size_t)D_SZ * D_SZ;
  float*  cf   = (float*)(wc16 + (size_t)D_SZ * D_SZ);
  float*  pw   = cf + (size_t)B_SZ * NCH * D_SZ;
  bf16_t* xs16 = u16;                       // u16 dead after GEMM1
  bf16_t* y16  = xb16;                      // xb16 dead after apply

  const int nblk = (B_SZ * L_SZ / BM) * (D_SZ / BN);   // 1024

  conv_bf16_k<<<2048, 256, 0, stream>>>(u, u16, (int)NBLD);
  conv_bf16_k<<<512, 256, 0, stream>>>(W_b, wb16, D_SZ * D_SZ);
  conv_bf16_k<<<512, 256, 0, stream>>>(W_c, wc16, D_SZ * D_SZ);
  pow_k<<<CHT, 256, 0, stream>>>(log_a, pw);

  gemm256<0><<<nblk, 512, 0, stream>>>(u16, wb16, xb16, pw, cf);
  scan_carry_k<<<dim3(D_SZ / 256, B_SZ), 256, 0, stream>>>(log_a, cf);
  scan_apply_k<<<dim3(L_SZ, B_SZ), 128, 0, stream>>>(xb16, pw, cf, xs16);
  gemm256<1><<<nblk, 512, 0, stream>>>(xs16, wc16, y16, nullptr, nullptr);
  ln_k<<<B_SZ * L_SZ, 256, 0, stream>>>(y16, gamma, beta, out);
}

// Round 8
// 253.301 us; speedup vs baseline: 1.0753x; 1.0753x over previous
//
#include <hip/hip_runtime.h>
#include <hip/hip_bf16.h>
#include <math.h>

#define B_SZ 8
#define L_SZ 4096
#define D_SZ 1024
#define CHT  64
#define NCH  (L_SZ / CHT)

typedef __bf16 bf16_t;
typedef bf16_t bf16x8 __attribute__((ext_vector_type(8)));
typedef bf16_t bf16x4 __attribute__((ext_vector_type(4)));
typedef float  f32x4  __attribute__((ext_vector_type(4)));

#define BM 256
#define BN 256
#define BK 64
#define NT 16              // K-tiles (1024/64)
#define EP_P 68            // epilogue strip padded width (f32)

__device__ __forceinline__ void gld16(const void* g, void* l) {
  __builtin_amdgcn_global_load_lds(
      (const __attribute__((address_space(1))) void*)g,
      (__attribute__((address_space(3))) void*)l, 16, 0, 0);
}

#define MFMA16(a, b, c) __builtin_amdgcn_mfma_f32_16x16x32_bf16(a, b, c, 0, 0, 0)

// C[m,n] = sum_k A[m,k]*Wt[n,k]; A,Wt bf16 row-major [.,1024]; C bf16.
// 256x256 tile, 8 waves (2M x 4N, wave tile 128x64), BK=64.
// 2-dbuf LDS (A: 2x32KB @0, B: 2x32KB @64KB), half-tile staggered staging,
// 4 phases/K-tile a 16 MFMA (quadrants mi-half x ni-half, frag reuse),
// 3-bit XOR chunk swizzle: LDS[row][ch] = global[row][ch ^ (row&7)] (16B chunks).
// MODE 0: fused per-64-chunk scan in epilogue, chunk finals -> cf.
// MODE 1: plain bf16 store.
template<int MODE>
__global__ __launch_bounds__(512, 2)
void gemm256(const bf16_t* __restrict__ A, const bf16_t* __restrict__ Wt,
             bf16_t* __restrict__ Cg, const float* __restrict__ pw,
             float* __restrict__ cf) {
  __shared__ __align__(16) char smem[131072];   // 128 KiB; epilogue strip aliases
  const int tid  = threadIdx.x;
  const int lane = tid & 63;
  const int wave = tid >> 6;
  const int wm = wave >> 2, wn = wave & 3;      // 2M x 4N
  const int fr = lane & 15, g = lane >> 4;

  // XCD-chunked bijective swizzle: 512 blocks = 8 XCDs x 64
  const int flat = (blockIdx.x & 7) * 64 + (blockIdx.x >> 3);
  const int bx = flat & 3, by = flat >> 2;
  const int brow = by * BM, bcol = bx * BN;

  // ---- staging source (pre-swizzled global; LDS dest linear)
  const int srow = lane >> 3;                   // 0..7
  const int sc   = (lane & 7) ^ srow;           // swizzled 16B chunk
  const bf16_t* aSrc = A  + (size_t)(brow + wave * 8 + srow) * 1024 + sc * 8;
  const bf16_t* bSrc = Wt + (size_t)(bcol + wave * 8 + srow) * 1024 + sc * 8;

  // ---- read side: global chunk c of row r is at LDS chunk c^(r&7); r&7 == fr&7
  const int c0 = ((g)     ^ (fr & 7)) << 4;     // kstep 0
  const int c1 = ((4 + g) ^ (fr & 7)) << 4;     // kstep 1
  const int aoff = wm * 16384 + fr * 128;               // + slot*32768 + mi*2048
  const int boff = 65536 + (wn >> 1) * 16384 + ((wn & 1) * 64 + fr) * 128;  // + slot*32768 + ni*2048

  // stage half-tile (H) sub-group (I) of K-tile T into buffer base DB
#define STG_A(DB, H, I, T) gld16(aSrc + (size_t)((H) * 128 + (I) * 64) * 1024 + (T) * 64, \
                                 (DB) + (H) * 16384 + (I) * 8192 + wave * 1024)
#define STG_B(DB, H, I, T) gld16(bSrc + (size_t)((H) * 128 + (I) * 64) * 1024 + (T) * 64, \
                                 (DB) + 65536 + (H) * 16384 + (I) * 8192 + wave * 1024)

  f32x4 acc[8][4] = {};
  bf16x8 af[4][2], bfv[4][2];

  // prologue: stage K-tile 0 into slot 0
  {
    char* db = smem;
    STG_A(db, 0, 0, 0); STG_A(db, 0, 1, 0); STG_A(db, 1, 0, 0); STG_A(db, 1, 1, 0);
    STG_B(db, 0, 0, 0); STG_B(db, 0, 1, 0); STG_B(db, 1, 0, 0); STG_B(db, 1, 1, 0);
  }
  asm volatile("s_waitcnt vmcnt(0)" ::: "memory");
  __builtin_amdgcn_s_barrier();
  asm volatile("" ::: "memory");

  for (int t = 0; t < NT; ++t) {
    const int s = t & 1;
    const char* sb = smem + s * 32768;
    char* db = smem + (s ^ 1) * 32768;
    const bool pf = (t + 1 < NT);

    // ===== phase 1: read A mi0-3 (8) + B ni0-1 (4); stage next A-half0
#pragma unroll
    for (int m = 0; m < 4; ++m) {
      af[m][0] = *(const bf16x8*)(sb + aoff + m * 2048 + c0);
      af[m][1] = *(const bf16x8*)(sb + aoff + m * 2048 + c1);
    }
#pragma unroll
    for (int n = 0; n < 2; ++n) {
      bfv[n][0] = *(const bf16x8*)(sb + boff + n * 2048 + c0);
      bfv[n][1] = *(const bf16x8*)(sb + boff + n * 2048 + c1);
    }
    if (pf) { STG_A(db, 0, 0, t + 1); STG_A(db, 0, 1, t + 1); }
    __builtin_amdgcn_s_barrier(); asm volatile("" ::: "memory");
    __builtin_amdgcn_s_setprio(1);
#pragma unroll
    for (int m = 0; m < 4; ++m)
#pragma unroll
      for (int n = 0; n < 2; ++n) {
        acc[m][n] = MFMA16(af[m][0], bfv[n][0], acc[m][n]);
        acc[m][n] = MFMA16(af[m][1], bfv[n][1], acc[m][n]);
      }
    __builtin_amdgcn_s_setprio(0);
    __builtin_amdgcn_s_barrier(); asm volatile("" ::: "memory");

    // ===== phase 2: read B ni2-3 (4); stage next A-half1 + B-half0(i0)
#pragma unroll
    for (int n = 2; n < 4; ++n) {
      bfv[n][0] = *(const bf16x8*)(sb + boff + n * 2048 + c0);
      bfv[n][1] = *(const bf16x8*)(sb + boff + n * 2048 + c1);
    }
    if (pf) { STG_A(db, 1, 0, t + 1); STG_A(db, 1, 1, t + 1); STG_B(db, 0, 0, t + 1); }
    __builtin_amdgcn_s_barrier(); asm volatile("" ::: "memory");
    __builtin_amdgcn_s_setprio(1);
#pragma unroll
    for (int m = 0; m < 4; ++m)
#pragma unroll
      for (int n = 2; n < 4; ++n) {
        acc[m][n] = MFMA16(af[m][0], bfv[n][0], acc[m][n]);
        acc[m][n] = MFMA16(af[m][1], bfv[n][1], acc[m][n]);
      }
    __builtin_amdgcn_s_setprio(0);
    __builtin_amdgcn_s_barrier(); asm volatile("" ::: "memory");

    // ===== phase 3: read A mi4-7 (8, overwrite af); stage B-half0(i1) + B-half1
#pragma unroll
    for (int m = 0; m < 4; ++m) {
      af[m][0] = *(const bf16x8*)(sb + aoff + (4 + m) * 2048 + c0);
      af[m][1] = *(const bf16x8*)(sb + aoff + (4 + m) * 2048 + c1);
    }
    if (pf) { STG_B(db, 0, 1, t + 1); STG_B(db, 1, 0, t + 1); STG_B(db, 1, 1, t + 1); }
    __builtin_amdgcn_s_barrier(); asm volatile("" ::: "memory");
    __builtin_amdgcn_s_setprio(1);
#pragma unroll
    for (int m = 0; m < 4; ++m)
#pragma unroll
      for (int n = 0; n < 2; ++n) {
        acc[4 + m][n] = MFMA16(af[m][0], bfv[n][0], acc[4 + m][n]);
        acc[4 + m][n] = MFMA16(af[m][1], bfv[n][1], acc[4 + m][n]);
      }
    __builtin_amdgcn_s_setprio(0);
    __builtin_amdgcn_s_barrier(); asm volatile("" ::: "memory");

    // ===== phase 4: no reads/stage; MFMA then per-K-tile vmcnt
    __builtin_amdgcn_s_setprio(1);
#pragma unroll
    for (int m = 0; m < 4; ++m)
#pragma unroll
      for (int n = 2; n < 4; ++n) {
        acc[4 + m][n] = MFMA16(af[m][0], bfv[n][0], acc[4 + m][n]);
        acc[4 + m][n] = MFMA16(af[m][1], bfv[n][1], acc[4 + m][n]);
      }
    __builtin_amdgcn_s_setprio(0);
    asm volatile("s_waitcnt vmcnt(0)" ::: "memory");
    __builtin_amdgcn_s_barrier();
    asm volatile("" ::: "memory");
  }
#undef STG_A
#undef STG_B

  // ---- epilogue: 4 column-strips of 64; strip LDS [256][EP_P] f32 aliases staging
  __syncthreads();
  float* strip = (float*)smem;
  const int bb  = by >> 4;             // batch (16 row-blocks of 256 per batch)
  const int cg0 = (by & 15) * 4;       // first global chunk of this block
#pragma unroll 1
  for (int q = 0; q < 4; ++q) {
    if (wn == q) {
#pragma unroll
      for (int mi = 0; mi < 8; ++mi)
#pragma unroll
        for (int ni = 0; ni < 4; ++ni)
#pragma unroll
          for (int r = 0; r < 4; ++r)
            strip[(wm * 128 + mi * 16 + g * 4 + r) * EP_P + ni * 16 + fr] = acc[mi][ni][r];
    }
    __syncthreads();
    if constexpr (MODE == 0) {
      if (tid < 256) {
        const int col = tid & 63;
        const int ch  = tid >> 6;       // chunk 0..3
        const int d   = bcol + q * 64 + col;
        const float a = pw[d];          // pw[0][d] = a_d
        float s = 0.f;
#pragma unroll 1
        for (int grp = 0; grp < 4; ++grp) {
          float v[16];
#pragma unroll
          for (int u = 0; u < 16; ++u) v[u] = strip[(ch * 64 + grp * 16 + u) * EP_P + col];
#pragma unroll
          for (int u = 0; u < 16; ++u) { s = a * s + v[u]; v[u] = s; }
#pragma unroll
          for (int u = 0; u < 16; ++u) strip[(ch * 64 + grp * 16 + u) * EP_P + col] = v[u];
        }
        cf[((size_t)(bb * NCH + cg0 + ch)) * D_SZ + d] = s;
      }
      __syncthreads();
    }
#pragma unroll
    for (int j = 0; j < 4; ++j) {
      const int u = j * 512 + tid;
      const int row = u >> 3;
      const int cu = (u & 7) * 8;
      f32x4 lo = *(const f32x4*)&strip[row * EP_P + cu];
      f32x4 hi = *(const f32x4*)&strip[row * EP_P + cu + 4];
      bf16x8 h;
#pragma unroll
      for (int jj = 0; jj < 4; ++jj) { h[jj] = (bf16_t)lo[jj]; h[4 + jj] = (bf16_t)hi[jj]; }
      *(bf16x8*)&Cg[(size_t)(brow + row) * 1024 + bcol + q * 64 + cu] = h;
    }
    __syncthreads();
  }
}

// fp32 -> bf16 grid-stride convert
__global__ __launch_bounds__(256)
void conv_bf16_k(const float* __restrict__ src, bf16_t* __restrict__ dst, int n) {
  int i = (blockIdx.x * 256 + threadIdx.x) * 4;
  const int stride = gridDim.x * 256 * 4;
  for (; i < n; i += stride) {
    f32x4 v = *(const f32x4*)(src + i);
    bf16x4 h;
#pragma unroll
    for (int j = 0; j < 4; ++j) h[j] = (bf16_t)v[j];
    *(bf16x4*)(dst + i) = h;
  }
}

// pw[t][d] = a_d^(t+1)
__global__ __launch_bounds__(256)
void pow_k(const float* __restrict__ log_a, float* __restrict__ pw) {
  const int t = blockIdx.x;
  const int d = threadIdx.x * 4;
#pragma unroll
  for (int j = 0; j < 4; ++j)
    pw[t * D_SZ + d + j] = expf(log_a[d + j] * (float)(t + 1));
}

// sequential scan over chunk finals with factor a^CHT, in place
__global__ __launch_bounds__(256)
void scan_carry_k(const float* __restrict__ log_a, float* __restrict__ cf) {
  const int d = blockIdx.x * 256 + threadIdx.x;
  const int b = blockIdx.y;
  const float aT = expf(log_a[d] * (float)CHT);
  float s = 0.f;
  for (int c = 0; c < NCH; ++c) {
    const size_t idx = ((size_t)(b * NCH + c)) * D_SZ + d;
    s = aT * s + cf[idx];
    cf[idx] = s;
  }
}

// states = xb16 + a^(t+1)*S_{c-1}; write bf16 for GEMM2
__global__ __launch_bounds__(128)
void scan_apply_k(const bf16_t* __restrict__ xb16, const float* __restrict__ pw,
                  const float* __restrict__ cf, bf16_t* __restrict__ xs16) {
  const int d8 = threadIdx.x * 8;
  const int l = blockIdx.x;
  const int b = blockIdx.y;
  const int c = l >> 6;
  const int t = l & (CHT - 1);
  const size_t idx = ((size_t)(b * L_SZ + l)) * D_SZ + d8;
  bf16x8 hv = *(const bf16x8*)(xb16 + idx);
  float s[8];
#pragma unroll
  for (int j = 0; j < 8; ++j) s[j] = (float)hv[j];
  if (c > 0) {
    f32x4 p0  = *(const f32x4*)(pw + t * D_SZ + d8);
    f32x4 p1  = *(const f32x4*)(pw + t * D_SZ + d8 + 4);
    const float* cb = cf + ((size_t)(b * NCH + (c - 1))) * D_SZ + d8;
    f32x4 v0 = *(const f32x4*)cb;
    f32x4 v1 = *(const f32x4*)(cb + 4);
#pragma unroll
    for (int j = 0; j < 4; ++j) { s[j] += p0[j] * v0[j]; s[4 + j] += p1[j] * v1[j]; }
  }
  bf16x8 h;
#pragma unroll
  for (int j = 0; j < 8; ++j) h[j] = (bf16_t)s[j];
  *(bf16x8*)(xs16 + idx) = h;
}

// LayerNorm over D=1024 (bf16 input, fp32 output), one block per row
__global__ __launch_bounds__(256)
void ln_k(const bf16_t* __restrict__ y, const float* __restrict__ gamma,
          const float* __restrict__ beta, float* __restrict__ out) {
  const size_t row = blockIdx.x;
  const int tid = threadIdx.x;
  bf16x4 h = *(const bf16x4*)(y + row * D_SZ + tid * 4);
  float v[4];
#pragma unroll
  for (int j = 0; j < 4; ++j) v[j] = (float)h[j];
  float s  = v[0] + v[1] + v[2] + v[3];
  float sq = v[0] * v[0] + v[1] * v[1] + v[2] * v[2] + v[3] * v[3];
#pragma unroll
  for (int off = 32; off; off >>= 1) {
    s  += __shfl_down(s, off);
    sq += __shfl_down(sq, off);
  }
  __shared__ float red[8];
  const int wid = tid >> 6;
  if ((tid & 63) == 0) { red[wid] = s; red[4 + wid] = sq; }
  __syncthreads();
  s  = red[0] + red[1] + red[2] + red[3];
  sq = red[4] + red[5] + red[6] + red[7];
  const float mean = s * (1.f / D_SZ);
  const float var  = sq * (1.f / D_SZ) - mean * mean;
  const float inv  = rsqrtf(var + 1e-5f);
  f32x4 gm = *(const f32x4*)(gamma + tid * 4);
  f32x4 bt = *(const f32x4*)(beta  + tid * 4);
  f32x4 o;
#pragma unroll
  for (int j = 0; j < 4; ++j) o[j] = (v[j] - mean) * inv * gm[j] + bt[j];
  *(f32x4*)(out + row * D_SZ + tid * 4) = o;
}

extern "C" void kernel_launch(void* const* d_in, const int* in_sizes, int n_in,
                              void* d_out, int out_size, void* d_ws, size_t ws_size,
                              hipStream_t stream) {
  const float* u     = (const float*)d_in[0];
  const float* log_a = (const float*)d_in[1];
  const float* W_b   = (const float*)d_in[2];
  const float* W_c   = (const float*)d_in[3];
  const float* gamma = (const float*)d_in[4];
  const float* beta  = (const float*)d_in[5];
  float* out = (float*)d_out;

  const size_t NBLD = (size_t)B_SZ * L_SZ * D_SZ;
  bf16_t* u16  = (bf16_t*)d_ws;             // bf16 u; xs16 aliases after GEMM1
  bf16_t* xb16 = u16 + NBLD;                // GEMM1 out (locally scanned); y16 aliases
  bf16_t* wb16 = xb16 + NBLD;
  bf16_t* wc16 = wb16 + (size_t)D_SZ * D_SZ;
  float*  cf   = (float*)(wc16 + (size_t)D_SZ * D_SZ);
  float*  pw   = cf + (size_t)B_SZ * NCH * D_SZ;
  bf16_t* xs16 = u16;                       // u16 dead after GEMM1
  bf16_t* y16  = xb16;                      // xb16 dead after apply

  const int nblk = (B_SZ * L_SZ / BM) * (D_SZ / BN);   // 512

  conv_bf16_k<<<2048, 256, 0, stream>>>(u, u16, (int)NBLD);
  conv_bf16_k<<<512, 256, 0, stream>>>(W_b, wb16, D_SZ * D_SZ);
  conv_bf16_k<<<512, 256, 0, stream>>>(W_c, wc16, D_SZ * D_SZ);
  pow_k<<<CHT, 256, 0, stream>>>(log_a, pw);

  gemm256<0><<<nblk, 512, 0, stream>>>(u16, wb16, xb16, pw, cf);
  scan_carry_k<<<dim3(D_SZ / 256, B_SZ), 256, 0, stream>>>(log_a, cf);
  scan_apply_k<<<dim3(L_SZ, B_SZ), 128, 0, stream>>>(xb16, pw, cf, xs16);
  gemm256<1><<<nblk, 512, 0, stream>>>(xs16, wc16, y16, nullptr, nullptr);
  ln_k<<<B_SZ * L_SZ, 256, 0, stream>>>(y16, gamma, beta, out);
}